// Round 8
// baseline (265.447 us; speedup 1.0000x reference)
//
#include <hip/hip_runtime.h>
#include <cmath>

// SVC_63737314673237 round 8: bf16 2-plane MFMA GEMM, slim registers +
// conflict-free stride-40 LDS.
// R7 post-mortem: launch_bounds(256,3) + tloc[8][9] forced AGPR/scratch
// spill (VGPR 84 < live demand ~180; 229MB FETCH / 156MB WRITE phantom
// traffic). Fixes: (1) per-chunk epilogue flush (butterfly + LDS atomic)
// removes the 72-reg tloc; (2) LDS row stride 40 f16 (80B) kills the
// 4-way frag-read conflicts (7864320 counter constant in R2/R3/R7);
// (3) launch_bounds(256,2) so the allocator is never forced to spill.

#define GAMMA 0.01f
constexpr int N  = 8192;
constexpr int D  = 256;
constexpr int S  = 5000;
constexpr int C  = 10;
constexpr int NV = 500;
constexpr int R  = 9;   // C-1
constexpr int LW = 40;  // LDS row stride in bf16 units (80 B)

typedef short s16x8 __attribute__((ext_vector_type(8)));  // 8 bf16
typedef short s16x4 __attribute__((ext_vector_type(4)));
typedef float f32x4 __attribute__((ext_vector_type(4)));

__device__ inline unsigned short bf16_rne(float f) {
    unsigned u = __float_as_uint(f);
    return (unsigned short)((u + 0x7FFFu + ((u >> 16) & 1u)) >> 16);
}

// ---------------- split into 2 bf16 planes + norms: one wave per row --------
__global__ __launch_bounds__(256) void prep_kernel(const float* __restrict__ x,
                                                   const float* __restrict__ sv,
                                                   unsigned short* __restrict__ xbh,
                                                   unsigned short* __restrict__ xbl,
                                                   unsigned short* __restrict__ sbh,
                                                   unsigned short* __restrict__ sbl,
                                                   float* __restrict__ xn,
                                                   float* __restrict__ svn) {
    int gid  = blockIdx.x * blockDim.x + threadIdx.x;
    int wid  = gid >> 6;
    int lane = gid & 63;
    if (wid >= N + S) return;
    bool isx = wid < N;
    int  r   = isx ? wid : wid - N;
    const float* row = isx ? (x + (size_t)r * D) : (sv + (size_t)r * D);
    float4 v = reinterpret_cast<const float4*>(row)[lane];
    float s = v.x * v.x + v.y * v.y + v.z * v.z + v.w * v.w;
#pragma unroll
    for (int off = 32; off > 0; off >>= 1) s += __shfl_xor(s, off, 64);
    float vv[4] = {v.x, v.y, v.z, v.w};
    s16x4 h, l;
#pragma unroll
    for (int k = 0; k < 4; ++k) {
        unsigned short hb = bf16_rne(vv[k]);
        float hf = __uint_as_float((unsigned)hb << 16);
        h[k] = (short)hb;
        l[k] = (short)bf16_rne(vv[k] - hf);
    }
    size_t o = (size_t)r * D + lane * 4;
    *(s16x4*)((isx ? xbh : sbh) + o) = h;
    *(s16x4*)((isx ? xbl : sbl) + o) = l;
    if (lane == 0) (isx ? xn : svn)[r] = s;
}

// ---------------- bf16 2-plane MFMA GEMM + per-chunk fused epilogue ---------
// grid (128 row tiles, 10 classes); 4 waves 2x2; wave tile 32x64 = 2x4 tiles
// of mfma_f32_16x16x32_bf16, 3 MFMAs/tile (hh,hl,lh) into ONE f32 acc.
__global__ __launch_bounds__(256, 2) void svc_gemm(
        const unsigned short* __restrict__ xbh,
        const unsigned short* __restrict__ xbl,
        const unsigned short* __restrict__ sbh,
        const unsigned short* __restrict__ sbl,
        const float* __restrict__ a,
        const float* __restrict__ xnorm,
        const float* __restrict__ svnorm,
        float* __restrict__ T) {
    __shared__ __align__(16) short As[2][64 * LW];    // 10 KB
    __shared__ __align__(16) short Bs[2][128 * LW];   // 20 KB
    __shared__ float tred[64 * R];                    // 2.25 KB

    const int tid  = threadIdx.x;
    const int n0   = blockIdx.x * 64;
    const int cls  = blockIdx.y;
    const int w    = tid >> 6;
    const int lane = tid & 63;
    const int wm   = w >> 1;
    const int wn   = w & 1;
    const int lx   = lane & 15;
    const int quad = lane >> 4;

    for (int i = tid; i < 64 * R; i += 256) tred[i] = 0.0f;

    // frag read offsets (bf16 units), stride-40 rows (conflict-free)
    int aoff[2], boff[4];
#pragma unroll
    for (int ti = 0; ti < 2; ++ti)
        aoff[ti] = (wm * 32 + ti * 16 + lx) * LW + quad * 8;
#pragma unroll
    for (int tj = 0; tj < 4; ++tj)
        boff[tj] = (wn * 64 + tj * 16 + lx) * LW + quad * 8;

    // staging maps
    const int srow = tid >> 2, sks = tid & 3;
    const int adst  = srow * LW + sks * 8;
    const int bdst0 = srow * LW + sks * 8;
    const int bdst1 = (64 + srow) * LW + sks * 8;
    const size_t abase = (size_t)(n0 + srow) * D + sks * 8;
    const int segend = cls * NV + NV - 1;

    // per-lane x norms for this lane's 8 output rows (live whole kernel)
    float xnv[8];
#pragma unroll
    for (int i = 0; i < 8; ++i)
        xnv[i] = xnorm[n0 + wm * 32 + (i >> 2) * 16 + quad * 4 + (i & 3)];

    f32x4 acc[2][4];
#pragma unroll
    for (int ti = 0; ti < 2; ++ti)
#pragma unroll
        for (int tj = 0; tj < 4; ++tj) acc[ti][tj] = (f32x4){0.f, 0.f, 0.f, 0.f};

    __syncthreads();

    for (int ch = 0; ch < 4; ++ch) {
        int svr0 = cls * NV + ch * 128 + srow;       if (svr0 > segend) svr0 = segend;
        int svr1 = cls * NV + ch * 128 + 64 + srow;  if (svr1 > segend) svr1 = segend;
        const size_t b0 = (size_t)svr0 * D + sks * 8;
        const size_t b1 = (size_t)svr1 * D + sks * 8;

        for (int kb = 0; kb < 8; ++kb) {
            const int ko = kb * 32;
            s16x8 vAh  = *(const s16x8*)(xbh + abase + ko);
            s16x8 vAl  = *(const s16x8*)(xbl + abase + ko);
            s16x8 vB0h = *(const s16x8*)(sbh + b0 + ko);
            s16x8 vB0l = *(const s16x8*)(sbl + b0 + ko);
            s16x8 vB1h = *(const s16x8*)(sbh + b1 + ko);
            s16x8 vB1l = *(const s16x8*)(sbl + b1 + ko);
            *(s16x8*)(&As[0][adst])  = vAh;
            *(s16x8*)(&As[1][adst])  = vAl;
            *(s16x8*)(&Bs[0][bdst0]) = vB0h;
            *(s16x8*)(&Bs[1][bdst0]) = vB0l;
            *(s16x8*)(&Bs[0][bdst1]) = vB1h;
            *(s16x8*)(&Bs[1][bdst1]) = vB1l;
            __syncthreads();

            s16x8 Ah[2], Al[2];
#pragma unroll
            for (int ti = 0; ti < 2; ++ti) {
                Ah[ti] = *(const s16x8*)(&As[0][aoff[ti]]);
                Al[ti] = *(const s16x8*)(&As[1][aoff[ti]]);
            }
#pragma unroll
            for (int tj = 0; tj < 4; ++tj) {
                s16x8 Bh = *(const s16x8*)(&Bs[0][boff[tj]]);
                s16x8 Bl = *(const s16x8*)(&Bs[1][boff[tj]]);
#pragma unroll
                for (int ti = 0; ti < 2; ++ti) {
                    acc[ti][tj] = __builtin_amdgcn_mfma_f32_16x16x32_bf16(
                        Ah[ti], Bh, acc[ti][tj], 0, 0, 0);
                    acc[ti][tj] = __builtin_amdgcn_mfma_f32_16x16x32_bf16(
                        Ah[ti], Bl, acc[ti][tj], 0, 0, 0);
                    acc[ti][tj] = __builtin_amdgcn_mfma_f32_16x16x32_bf16(
                        Al[ti], Bh, acc[ti][tj], 0, 0, 0);
                }
            }
            __syncthreads();
        }

        // per-chunk epilogue: exp + weighted reduce, flushed to tred (LDS).
        // No LDS-tile access here -> safe to overlap with next chunk's stores.
        float av[4][R], snv[4];
#pragma unroll
        for (int tj = 0; tj < 4; ++tj) {
            int cseg = ch * 128 + wn * 64 + tj * 16 + lx;
            bool ok = cseg < NV;
            snv[tj] = svnorm[cls * NV + (ok ? cseg : NV - 1)];
#pragma unroll
            for (int r = 0; r < R; ++r)
                av[tj][r] = ok ? a[(size_t)r * S + cls * NV + cseg] : 0.0f;
        }
#pragma unroll
        for (int ti = 0; ti < 2; ++ti)
#pragma unroll
            for (int reg = 0; reg < 4; ++reg) {
                float xn = xnv[ti * 4 + reg];
                float kv[4];
#pragma unroll
                for (int tj = 0; tj < 4; ++tj)
                    kv[tj] = __expf(fmaf(2.0f * GAMMA, acc[ti][tj][reg],
                                         -GAMMA * (xn + snv[tj])));
                int row = wm * 32 + ti * 16 + quad * 4 + reg;
#pragma unroll
                for (int r = 0; r < R; ++r) {
                    float v = av[0][r] * kv[0];
                    v = fmaf(av[1][r], kv[1], v);
                    v = fmaf(av[2][r], kv[2], v);
                    v = fmaf(av[3][r], kv[3], v);
                    v += __shfl_xor(v, 1, 64);
                    v += __shfl_xor(v, 2, 64);
                    v += __shfl_xor(v, 4, 64);
                    v += __shfl_xor(v, 8, 64);
                    if (lx == 0) atomicAdd(&tred[row * R + r], v);
                }
            }
#pragma unroll
        for (int ti = 0; ti < 2; ++ti)
#pragma unroll
            for (int tj = 0; tj < 4; ++tj)
                acc[ti][tj] = (f32x4){0.f, 0.f, 0.f, 0.f};
    }

    __syncthreads();
    for (int i = tid; i < 64 * R; i += 256) {
        int row = i / R, r = i - row * R;
        T[(size_t)(n0 + row) * 90 + r * 10 + cls] = tred[i];
    }
}

// ---------------- pairwise voting + argmax ----------------------------------
__global__ __launch_bounds__(256) void vote_kernel(const float* __restrict__ T,
                                                   const float* __restrict__ b,
                                                   int* __restrict__ out) {
    int n = blockIdx.x * blockDim.x + threadIdx.x;
    if (n >= N) return;
    const float* Tn = T + (size_t)n * 90;
    float tv[90];
#pragma unroll
    for (int i = 0; i < 90; ++i) tv[i] = Tn[i];
    int counts[C];
#pragma unroll
    for (int k = 0; k < C; ++k) counts[k] = 0;
    int p = 0;
#pragma unroll
    for (int i = 0; i < C; ++i) {
#pragma unroll
        for (int j = i + 1; j < C; ++j) {
            float c = tv[i * 10 + j] + tv[(j - 1) * 10 + i] + b[p];
            if (c > 0.f) counts[i]++; else counts[j]++;
            ++p;
        }
    }
    int best = 0;
#pragma unroll
    for (int k = 1; k < C; ++k)
        if (counts[k] > counts[best]) best = k;
    out[n]     = best;
    out[N + n] = best;
}

extern "C" void kernel_launch(void* const* d_in, const int* in_sizes, int n_in,
                              void* d_out, int out_size, void* d_ws, size_t ws_size,
                              hipStream_t stream) {
    const float* x  = (const float*)d_in[0];   // [8192,256]
    const float* sv = (const float*)d_in[1];   // [5000,256]
    const float* a  = (const float*)d_in[2];   // [9,5000]
    const float* b  = (const float*)d_in[3];   // [45]
    int* out = (int*)d_out;

    char* wp = (char*)d_ws;
    unsigned short* xbh = (unsigned short*)wp;  wp += (size_t)N * D * 2;
    unsigned short* xbl = (unsigned short*)wp;  wp += (size_t)N * D * 2;
    unsigned short* sbh = (unsigned short*)wp;  wp += (size_t)S * D * 2;
    unsigned short* sbl = (unsigned short*)wp;  wp += (size_t)S * D * 2;
    float* xnorm  = (float*)wp;                 wp += (size_t)N * 4;
    float* svnorm = (float*)wp;                 wp += (size_t)S * 4;
    float* T      = (float*)wp;

    {   // split + norms
        int waves = N + S;
        prep_kernel<<<(waves * 64 + 255) / 256, 256, 0, stream>>>(
            x, sv, xbh, xbl, sbh, sbl, xnorm, svnorm);
    }
    {   // GEMM
        dim3 grid(N / 64, C);
        svc_gemm<<<grid, 256, 0, stream>>>(xbh, xbl, sbh, sbl, a, xnorm, svnorm, T);
    }
    {   // voting
        vote_kernel<<<N / 256, 256, 0, stream>>>(T, b, out);
    }
}